// Round 5
// baseline (361.006 us; speedup 1.0000x reference)
//
#include <hip/hip_runtime.h>

#define N_NODES   100000
#define N_EDGES   1600000
#define N_FEAT    128
#define HIDDEN    64
#define NUM_GRAPHS 64
#define SCAN_BLOCKS ((N_NODES + 255) / 256)   // 391
#define XPAD 130                              // LDS row stride: bank=(2r+k)%32 -> 2-way (free)
#define N_SHARD 8
#define SHARD_SZ (N_NODES / N_SHARD)          // 12500
#define CSR_CHUNK 8192

// ---------------------------------------------------------------------------
// K1: h = x @ W. lane = row (64 rows/block tile), wave w computes cols
// [16w,16w+16). x staged in LDS (pad 130); W read via wave-uniform scalar
// loads -> SGPR operand of v_fma.
// ---------------------------------------------------------------------------
__global__ __launch_bounds__(256) void gemm_xw(const float* __restrict__ x,
                                               const float* __restrict__ W,
                                               float* __restrict__ h) {
    __shared__ float xs[64 * XPAD];            // 33.3 KB
    const int tid  = threadIdx.x;
    const int lane = tid & 63;
    const int wid  = __builtin_amdgcn_readfirstlane(tid >> 6);  // force wave-uniform
    const int c0   = wid * 16;
    const int base = blockIdx.x * 64;

#pragma unroll
    for (int j = 0; j < 8; ++j) {
        const int flat = (tid + j * 256) * 4;
        const int r = flat >> 7, k = flat & 127;
        const int row = base + r;
        float4 v = make_float4(0.f, 0.f, 0.f, 0.f);
        if (row < N_NODES) v = *(const float4*)&x[(size_t)row * N_FEAT + k];
        xs[r * XPAD + k + 0] = v.x;
        xs[r * XPAD + k + 1] = v.y;
        xs[r * XPAD + k + 2] = v.z;
        xs[r * XPAD + k + 3] = v.w;
    }
    __syncthreads();

    float acc[16];
#pragma unroll
    for (int c = 0; c < 16; ++c) acc[c] = 0.f;

    const float* __restrict__ Wp = W + c0;     // wave-uniform pointer
#pragma unroll 4
    for (int k = 0; k < N_FEAT; ++k) {
        const float xv = xs[lane * XPAD + k];
#pragma unroll
        for (int c = 0; c < 16; ++c)
            acc[c] = fmaf(xv, Wp[k * HIDDEN + c], acc[c]);
    }

    const int row = base + lane;
    if (row < N_NODES) {
        float* hp = &h[(size_t)row * HIDDEN + c0];
#pragma unroll
        for (int c = 0; c < 16; c += 4)
            *(float4*)&hp[c] = make_float4(acc[c], acc[c + 1], acc[c + 2], acc[c + 3]);
    }
}

// ---------------------------------------------------------------------------
// K2: deg[dst] += 1 per edge (deg pre-zeroed; +1 self-loop applied in dis)
// ---------------------------------------------------------------------------
__global__ __launch_bounds__(256) void deg_kernel(const int* __restrict__ ei,
                                                  int* __restrict__ deg) {
    const int e = blockIdx.x * 256 + threadIdx.x;
    if (e < N_EDGES) atomicAdd(&deg[__builtin_nontemporal_load(&ei[N_EDGES + e])], 1);
}

// ---------------------------------------------------------------------------
// K3: dis[i] = rsqrt(deg[i] + 1)
// ---------------------------------------------------------------------------
__global__ __launch_bounds__(256) void dis_kernel(const int* __restrict__ deg,
                                                  float* __restrict__ dis) {
    const int i = blockIdx.x * 256 + threadIdx.x;
    if (i < N_NODES) dis[i] = rsqrtf((float)deg[i] + 1.0f);
}

// ---------------------------------------------------------------------------
// Scan (exclusive prefix sum of deg -> row_ptr), 3 small kernels.
// ---------------------------------------------------------------------------
__global__ __launch_bounds__(256) void scan1(const int* __restrict__ deg,
                                             int* __restrict__ row_ptr,
                                             int* __restrict__ bsum) {
    __shared__ int s[256];
    const int t = threadIdx.x;
    const int i = blockIdx.x * 256 + t;
    const int v = (i < N_NODES) ? deg[i] : 0;
    s[t] = v;
    __syncthreads();
    for (int off = 1; off < 256; off <<= 1) {
        const int add = (t >= off) ? s[t - off] : 0;
        __syncthreads();
        s[t] += add;
        __syncthreads();
    }
    if (i < N_NODES) row_ptr[i] = s[t] - v;   // exclusive
    if (t == 255) bsum[blockIdx.x] = s[255];
}

__global__ __launch_bounds__(512) void scan2(const int* __restrict__ bsum,
                                             int* __restrict__ boff) {
    __shared__ int s[512];
    const int t = threadIdx.x;
    const int v = (t < SCAN_BLOCKS) ? bsum[t] : 0;
    s[t] = v;
    __syncthreads();
    for (int off = 1; off < 512; off <<= 1) {
        const int add = (t >= off) ? s[t - off] : 0;
        __syncthreads();
        s[t] += add;
        __syncthreads();
    }
    if (t < SCAN_BLOCKS) boff[t] = s[t] - v;  // exclusive
}

__global__ __launch_bounds__(256) void scan3(int* __restrict__ row_ptr,
                                             const int* __restrict__ boff,
                                             int* __restrict__ next) {
    const int i = blockIdx.x * 256 + threadIdx.x;
    if (i < N_NODES) {
        const int r = row_ptr[i] + boff[i >> 8];
        row_ptr[i] = r;
        next[i] = r;
    }
}

// ---------------------------------------------------------------------------
// K4: CSR build, XCD-sharded + NON-TEMPORAL edge reads.
// nt loads keep the streaming edge list out of L2, so the shard's ~800 KB
// srcs write window stays resident in its XCD's L2 and the ~16 scattered
// 4B stores per 64B line combine before writeback (R4 showed streaming reads
// evicting the window -> 46 B/edge writeback).
// ---------------------------------------------------------------------------
__global__ __launch_bounds__(256) void csr_build(const int* __restrict__ ei,
                                                 int* __restrict__ next,
                                                 int* __restrict__ srcs) {
    const int shard = blockIdx.x & (N_SHARD - 1);
    const int base  = (blockIdx.x >> 3) * CSR_CHUNK;
    const int lo = shard * SHARD_SZ;
    const int hi = lo + SHARD_SZ;
    const int lim = min(base + CSR_CHUNK, N_EDGES);
    for (int e = base + threadIdx.x; e < lim; e += 256) {
        const int d = __builtin_nontemporal_load(&ei[N_EDGES + e]);
        if (d >= lo && d < hi) {
            const int s = __builtin_nontemporal_load(&ei[e]);
            const int pos = atomicAdd(&next[d], 1);
            srcs[pos] = s;
        }
    }
}

// ---------------------------------------------------------------------------
// K5: per-node gather-aggregate. One wave per node. Lane L handles edge
// subgroup L>>4, columns (L&15)*4..+3 as float4 (16B/lane gathers). Broadcast
// shuffles amortized to 2 per 4 edges; quarter partials reduced by shfl_xor.
// srcs is read-once streaming -> nt load keeps L2 free for hot h rows.
// ---------------------------------------------------------------------------
__global__ __launch_bounds__(256) void agg_kernel(const int* __restrict__ row_ptr,
                                                  const int* __restrict__ row_end,
                                                  const int* __restrict__ srcs,
                                                  const float* __restrict__ h,
                                                  const float* __restrict__ dis,
                                                  const float* __restrict__ bias,
                                                  float* __restrict__ hn) {
    const int node = blockIdx.x * 4 + (threadIdx.x >> 6);
    if (node >= N_NODES) return;
    const int lane = threadIdx.x & 63;
    const int q    = lane >> 4;        // edge subgroup within a 4-edge group
    const int c4   = (lane & 15) * 4;  // column group
    const int beg = row_ptr[node];
    const int end = row_end[node];
    const float dn = dis[node];
    float4 acc = make_float4(0.f, 0.f, 0.f, 0.f);

    for (int j0 = beg; j0 < end; j0 += 64) {
        const int n = min(64, end - j0);
        int s = 0; float w = 0.f;
        if (lane < n) { s = __builtin_nontemporal_load(&srcs[j0 + lane]); w = dis[s] * dn; }
        const int ng = (n + 3) >> 2;
        for (int i = 0; i < ng; ++i) {
            const int idx = i * 4 + q;          // edge index in chunk (w=0 pads tail)
            const int   si = __shfl(s, idx);
            const float wi = __shfl(w, idx);
            const float4 v = *(const float4*)&h[(size_t)si * HIDDEN + c4];
            acc.x = fmaf(v.x, wi, acc.x);
            acc.y = fmaf(v.y, wi, acc.y);
            acc.z = fmaf(v.z, wi, acc.z);
            acc.w = fmaf(v.w, wi, acc.w);
        }
    }
    // reduce the 4 quarter-partials (lanes c, c+16, c+32, c+48 share columns)
    acc.x += __shfl_xor(acc.x, 16); acc.y += __shfl_xor(acc.y, 16);
    acc.z += __shfl_xor(acc.z, 16); acc.w += __shfl_xor(acc.w, 16);
    acc.x += __shfl_xor(acc.x, 32); acc.y += __shfl_xor(acc.y, 32);
    acc.z += __shfl_xor(acc.z, 32); acc.w += __shfl_xor(acc.w, 32);

    if (lane < 16) {
        const float4 hv = *(const float4*)&h[(size_t)node * HIDDEN + c4];
        const float4 bv = *(const float4*)&bias[c4];
        const float d2 = dn * dn;
        float4 r;
        r.x = fmaxf(fmaf(hv.x, d2, acc.x) + bv.x, 0.f);
        r.y = fmaxf(fmaf(hv.y, d2, acc.y) + bv.y, 0.f);
        r.z = fmaxf(fmaf(hv.z, d2, acc.z) + bv.z, 0.f);
        r.w = fmaxf(fmaf(hv.w, d2, acc.w) + bv.w, 0.f);
        *(float4*)&hn[(size_t)node * HIDDEN + c4] = r;
    }
}

// ---------------------------------------------------------------------------
// K6: global_add_pool — parallel over node chunks; batch sorted, so each wave
// accumulates locally and flushes one atomic burst per graph switch.
// hn is read-once streaming -> nt loads.
// ---------------------------------------------------------------------------
__global__ __launch_bounds__(256) void pool_kernel(const float* __restrict__ hn,
                                                   const int* __restrict__ batch,
                                                   float* __restrict__ u) {
    const int chunk = blockIdx.x * 64;
    const int lane = threadIdx.x & 63;
    const int wv = threadIdx.x >> 6;
    const int lim = min(chunk + 64, N_NODES);
    float acc = 0.f;
    int cur_g = -1;
    for (int node = chunk + wv; node < lim; node += 4) {
        const int g = batch[node];
        if (g != cur_g) {
            if (cur_g >= 0) atomicAdd(&u[cur_g * HIDDEN + lane], acc);
            acc = 0.f;
            cur_g = g;
        }
        acc += __builtin_nontemporal_load(&hn[(size_t)node * HIDDEN + lane]);
    }
    if (cur_g >= 0) atomicAdd(&u[cur_g * HIDDEN + lane], acc);
}

// ---------------------------------------------------------------------------
// K7: out[g] = relu(u[g] @ W1 + b1) @ W2 + b2
// ---------------------------------------------------------------------------
__global__ __launch_bounds__(64) void mlp_kernel(const float* __restrict__ u,
                                                 const float* __restrict__ W1,
                                                 const float* __restrict__ b1,
                                                 const float* __restrict__ W2,
                                                 const float* __restrict__ b2,
                                                 float* __restrict__ out) {
    __shared__ float W1s[HIDDEN * 16];
    __shared__ float W2s[16];
    __shared__ float b1s[16];
    const int t = threadIdx.x;
    for (int i = t; i < HIDDEN * 16; i += 64) W1s[i] = W1[i];
    if (t < 16) { W2s[t] = W2[t]; b1s[t] = b1[t]; }
    __syncthreads();
    if (t < NUM_GRAPHS) {
        float uu[HIDDEN];
#pragma unroll
        for (int k = 0; k < HIDDEN; ++k) uu[k] = u[t * HIDDEN + k];
        float o = b2[0];
#pragma unroll
        for (int j = 0; j < 16; ++j) {
            float s = b1s[j];
#pragma unroll
            for (int k = 0; k < HIDDEN; ++k) s = fmaf(uu[k], W1s[k * 16 + j], s);
            o = fmaf(fmaxf(s, 0.f), W2s[j], o);
        }
        out[t] = o;
    }
}

// ---------------------------------------------------------------------------
extern "C" void kernel_launch(void* const* d_in, const int* in_sizes, int n_in,
                              void* d_out, int out_size, void* d_ws, size_t ws_size,
                              hipStream_t stream) {
    const float* x  = (const float*)d_in[0];
    const float* W  = (const float*)d_in[1];
    const float* b  = (const float*)d_in[2];
    const float* W1 = (const float*)d_in[3];
    const float* b1 = (const float*)d_in[4];
    const float* W2 = (const float*)d_in[5];
    const float* b2 = (const float*)d_in[6];
    const int*   ei = (const int*)d_in[7];     // [2, E] flat: src = ei[e], dst = ei[E+e]
    const int* batch = (const int*)d_in[8];    // [N], sorted
    float* out = (float*)d_out;

    float* h    = (float*)d_ws;
    float* hn   = h + (size_t)N_NODES * HIDDEN;
    int*   srcs = (int*)(hn + (size_t)N_NODES * HIDDEN);
    int*   deg  = srcs + N_EDGES;
    float* dis  = (float*)(deg + N_NODES);
    int*   row_ptr = (int*)(dis + N_NODES);
    int*   next    = row_ptr + N_NODES;
    int*   bsum    = next + N_NODES;
    int*   boff    = bsum + 512;
    float* u       = (float*)(boff + 512);

    hipMemsetAsync(deg, 0, N_NODES * sizeof(int), stream);
    hipMemsetAsync(u, 0, NUM_GRAPHS * HIDDEN * sizeof(float), stream);

    gemm_xw<<<(N_NODES + 63) / 64, 256, 0, stream>>>(x, W, h);
    deg_kernel<<<(N_EDGES + 255) / 256, 256, 0, stream>>>(ei, deg);
    dis_kernel<<<SCAN_BLOCKS, 256, 0, stream>>>(deg, dis);
    scan1<<<SCAN_BLOCKS, 256, 0, stream>>>(deg, row_ptr, bsum);
    scan2<<<1, 512, 0, stream>>>(bsum, boff);
    scan3<<<SCAN_BLOCKS, 256, 0, stream>>>(row_ptr, boff, next);
    csr_build<<<N_SHARD * ((N_EDGES + CSR_CHUNK - 1) / CSR_CHUNK), 256, 0, stream>>>(ei, next, srcs);
    agg_kernel<<<(N_NODES + 3) / 4, 256, 0, stream>>>(row_ptr, next, srcs, h, dis, b, hn);
    pool_kernel<<<(N_NODES + 63) / 64, 256, 0, stream>>>(hn, batch, u);
    mlp_kernel<<<1, 64, 0, stream>>>(u, W1, b1, W2, b2, out);
}